// Round 3
// baseline (556.865 us; speedup 1.0000x reference)
//
#include <hip/hip_runtime.h>

#define SDIM 10
#define HDIM 2048
#define LDIM 4096
#define BDIM 4

// 1/sqrt(2048)
#define KSCALE 0.02209708691207961f

// ---------------------------------------------------------------------------
// Kernel 1 (v2): one wave per output column o, all 4 batches in-wave.
// k[b,s,o] = sum_h h_l[b,s,h]*w_k[o,h]; v likewise with w_v.
// Weights w_k/w_v are read EXACTLY ONCE (was 4x: once per batch).
// h_l re-reads (320 KB x 2048 waves) hit L2. acc = 4b*10s*2mat = 80 VGPR.
// grid 512 blocks x 256 thr (4 waves) -> 2 blocks/CU; bounds (256,2) => no spill.
// ---------------------------------------------------------------------------
__global__ __launch_bounds__(256, 2) void kv_kernel(
    const float* __restrict__ h_l, const float* __restrict__ w_k,
    const float* __restrict__ w_v, float* __restrict__ k_out,
    float* __restrict__ v_out) {
  const int wave = threadIdx.x >> 6;
  const int lane = threadIdx.x & 63;
  const int o = blockIdx.x * 4 + wave;

  const float4* wk = (const float4*)(w_k + (size_t)o * HDIM);
  const float4* wv = (const float4*)(w_v + (size_t)o * HDIM);
  const float4* hl4 = (const float4*)h_l;  // [b][s][512]

  float ak[BDIM][SDIM], av[BDIM][SDIM];
#pragma unroll
  for (int b = 0; b < BDIM; b++)
#pragma unroll
    for (int s = 0; s < SDIM; s++) { ak[b][s] = 0.f; av[b][s] = 0.f; }

#pragma unroll
  for (int j = 0; j < 8; j++) {
    const int idx = j * 64 + lane;
    const float4 a = wk[idx];
    const float4 c = wv[idx];
#pragma unroll
    for (int b = 0; b < BDIM; b++)
#pragma unroll
      for (int s = 0; s < SDIM; s++) {
        const float4 h = hl4[(size_t)(b * SDIM + s) * 512 + idx];
        ak[b][s] += a.x * h.x + a.y * h.y + a.z * h.z + a.w * h.w;
        av[b][s] += c.x * h.x + c.y * h.y + c.z * h.z + c.w * h.w;
      }
  }
#pragma unroll
  for (int b = 0; b < BDIM; b++)
#pragma unroll
    for (int s = 0; s < SDIM; s++) {
#pragma unroll
      for (int d = 1; d < 64; d <<= 1) {
        ak[b][s] += __shfl_xor(ak[b][s], d);
        av[b][s] += __shfl_xor(av[b][s], d);
      }
    }
  if (lane == 0) {
#pragma unroll
    for (int b = 0; b < BDIM; b++)
#pragma unroll
      for (int s = 0; s < SDIM; s++) {
        const size_t base = ((size_t)b * SDIM + s) * HDIM + o;
        k_out[base] = ak[b][s];
        v_out[base] = av[b][s];
      }
  }
}

// ---------------------------------------------------------------------------
// Kernel 2a: kk partials. kk[b,s,h] = sum_o k[b,s,o]*w_q[o,h]. (unchanged)
// ---------------------------------------------------------------------------
#define OSPLIT 16
__global__ __launch_bounds__(256) void kk_part_kernel(
    const float* __restrict__ k_in, const float* __restrict__ w_q,
    float* __restrict__ part) {
  const int b = blockIdx.z;
  const int oc = blockIdx.y >> 1;
  const int s0 = (blockIdx.y & 1) * 5;
  const int f4 = blockIdx.x * 256 + threadIdx.x;  // float4 index in [0,512)

  __shared__ float ksh[5 * 128];
  for (int idx = threadIdx.x; idx < 5 * 128; idx += 256) {
    const int s = idx >> 7, oo = idx & 127;
    ksh[idx] = k_in[((size_t)b * SDIM + s0 + s) * HDIM + oc * 128 + oo];
  }
  __syncthreads();

  float4 acc[5];
#pragma unroll
  for (int s = 0; s < 5; s++) acc[s] = make_float4(0.f, 0.f, 0.f, 0.f);

  const float4* wq4 = (const float4*)w_q;
  for (int oo = 0; oo < 128; oo++) {
    const float4 w = wq4[(size_t)(oc * 128 + oo) * 512 + f4];
#pragma unroll
    for (int s = 0; s < 5; s++) {
      const float kv = ksh[s * 128 + oo];
      acc[s].x += kv * w.x; acc[s].y += kv * w.y;
      acc[s].z += kv * w.z; acc[s].w += kv * w.w;
    }
  }
#pragma unroll
  for (int s = 0; s < 5; s++) {
    ((float4*)part)[(((size_t)oc * BDIM + b) * SDIM + s0 + s) * 512 + f4] = acc[s];
  }
}

// Kernel 2b: reduce 16 partials -> kk. (unchanged)
__global__ __launch_bounds__(256) void kk_reduce_kernel(
    const float* __restrict__ part, float* __restrict__ kk_out) {
  const int t = blockIdx.x * 256 + threadIdx.x;  // [0, 20480)
  const float4* p4 = (const float4*)part;
  float4 acc = make_float4(0.f, 0.f, 0.f, 0.f);
#pragma unroll
  for (int p = 0; p < OSPLIT; p++) {
    const float4 v = p4[(size_t)p * 20480 + t];
    acc.x += v.x; acc.y += v.y; acc.z += v.z; acc.w += v.w;
  }
  ((float4*)kk_out)[t] = acc;
}

// ---------------------------------------------------------------------------
// Kernel 3 (v2): one wave per o, all 4 batches. w_o read exactly once.
// vo[b,s,o] = sum_h v[b,s,h]*w_o[o,h]. acc = 40 VGPR.
// ---------------------------------------------------------------------------
__global__ __launch_bounds__(256, 2) void vo_kernel(
    const float* __restrict__ v_in, const float* __restrict__ w_o,
    float* __restrict__ vo_out) {
  const int wave = threadIdx.x >> 6;
  const int lane = threadIdx.x & 63;
  const int o = blockIdx.x * 4 + wave;

  const float4* wo = (const float4*)(w_o + (size_t)o * HDIM);
  const float4* vb4 = (const float4*)v_in;  // [b][s][512]

  float a[BDIM][SDIM];
#pragma unroll
  for (int b = 0; b < BDIM; b++)
#pragma unroll
    for (int s = 0; s < SDIM; s++) a[b][s] = 0.f;

#pragma unroll
  for (int j = 0; j < 8; j++) {
    const int idx = j * 64 + lane;
    const float4 w = wo[idx];
#pragma unroll
    for (int b = 0; b < BDIM; b++)
#pragma unroll
      for (int s = 0; s < SDIM; s++) {
        const float4 h = vb4[(size_t)(b * SDIM + s) * 512 + idx];
        a[b][s] += w.x * h.x + w.y * h.y + w.z * h.z + w.w * h.w;
      }
  }
#pragma unroll
  for (int b = 0; b < BDIM; b++)
#pragma unroll
    for (int s = 0; s < SDIM; s++) {
#pragma unroll
      for (int d = 1; d < 64; d <<= 1) a[b][s] += __shfl_xor(a[b][s], d);
    }
  if (lane == 0) {
#pragma unroll
    for (int b = 0; b < BDIM; b++)
#pragma unroll
      for (int s = 0; s < SDIM; s++)
        vo_out[((size_t)b * SDIM + s) * HDIM + o] = a[b][s];
  }
}

// ---------------------------------------------------------------------------
// Kernel 4 (main) v4: block-level LDS sharing of kk/vo as in v3, but staging
// via __builtin_amdgcn_global_load_lds (no VGPR round-trip -> no spill) with
// LDS double-buffer (2 x 20 KB). Chunk j+1 issued after the barrier, before
// computing chunk j -> loads in flight under the FMAs (m97 pattern; the
// __syncthreads vmcnt-drain lands after a full compute phase).
// Register peak: he(64)+acc(20)+temps ~ 105; bounds (256,3) caps 168.
// ---------------------------------------------------------------------------
__device__ __forceinline__ void stage_chunk(const float4* __restrict__ src,
                                            float4* lds_base, int j, int tid,
                                            int wave) {
#pragma unroll
  for (int k = 0; k < 5; k++) {
    const int idx = k * 256 + tid;
    const float4* g = src + (size_t)(idx >> 7) * 512 + j * 128 + (idx & 127);
    float4* l = lds_base + k * 256 + (wave << 6);
    __builtin_amdgcn_global_load_lds(
        (const __attribute__((address_space(1))) void*)g,
        (__attribute__((address_space(3))) void*)l, 16, 0, 0);
  }
}

__global__ __launch_bounds__(256, 3) void attn_kernel(
    const float* __restrict__ h_e, const float* __restrict__ kk,
    const float* __restrict__ vo, const float* __restrict__ alpha_p,
    float* __restrict__ out) {
  const int b = blockIdx.y;
  const int wave = threadIdx.x >> 6;
  const int lane = threadIdx.x & 63;
  const int tid = threadIdx.x;
  const int row0 = blockIdx.x * 8 + wave * 2;
  const float alpha = *alpha_p;
  const float4* kkb = (const float4*)(kk + (size_t)b * SDIM * HDIM);
  const float4* vob = (const float4*)(vo + (size_t)b * SDIM * HDIM);
  const size_t rowbase = ((size_t)b * LDIM + row0) * HDIM;

  __shared__ float4 lds[2][SDIM * 128];  // 2 x 20 KB

  // h_e rows held in registers across both phases (64 VGPR).
  float4 he[2][8];
#pragma unroll
  for (int r = 0; r < 2; r++) {
    const float4* src = (const float4*)(h_e + rowbase + (size_t)r * HDIM);
#pragma unroll
    for (int i = 0; i < 8; i++) he[r][i] = src[i * 64 + lane];
  }

  float acc[2][SDIM];
#pragma unroll
  for (int r = 0; r < 2; r++)
#pragma unroll
    for (int s = 0; s < SDIM; s++) acc[r][s] = 0.f;

  // ---- QK phase ----
  stage_chunk(kkb, lds[0], 0, tid, wave);
#pragma unroll
  for (int j = 0; j < 4; j++) {
    __syncthreads();  // drains vmem: chunk j landed; buf (j+1)&1 consumed
    if (j < 3) stage_chunk(kkb, lds[(j + 1) & 1], j + 1, tid, wave);
    const float4* buf = lds[j & 1];
#pragma unroll
    for (int ii = 0; ii < 2; ii++) {
      const int i = j * 2 + ii;
#pragma unroll
      for (int s = 0; s < SDIM; s++) {
        const float4 kv = buf[s * 128 + ii * 64 + lane];
#pragma unroll
        for (int r = 0; r < 2; r++)
          acc[r][s] += he[r][i].x * kv.x + he[r][i].y * kv.y +
                       he[r][i].z * kv.z + he[r][i].w * kv.w;
      }
    }
  }

  // ---- scores -> softmax (per-wave) ----
#pragma unroll
  for (int r = 0; r < 2; r++)
#pragma unroll
    for (int s = 0; s < SDIM; s++) {
      float v = acc[r][s];
      v += __shfl_xor(v, 1);
      v += __shfl_xor(v, 2);
      v += __shfl_xor(v, 4);
      v += __shfl_xor(v, 8);
      v += __shfl_xor(v, 16);
      v += __shfl_xor(v, 32);
      acc[r][s] = v * KSCALE;
    }
#pragma unroll
  for (int r = 0; r < 2; r++) {
    float m = acc[r][0];
#pragma unroll
    for (int s = 1; s < SDIM; s++) m = fmaxf(m, acc[r][s]);
    float sum = 0.f;
#pragma unroll
    for (int s = 0; s < SDIM; s++) {
      acc[r][s] = __expf(acc[r][s] - m);
      sum += acc[r][s];
    }
    const float inv = alpha / sum;
#pragma unroll
    for (int s = 0; s < SDIM; s++) acc[r][s] *= inv;
  }

  // ---- PV phase ----
  stage_chunk(vob, lds[0], 0, tid, wave);
#pragma unroll
  for (int j = 0; j < 4; j++) {
    __syncthreads();  // drains PV chunk j; syncs prior-buffer consumption
    if (j < 3) stage_chunk(vob, lds[(j + 1) & 1], j + 1, tid, wave);
    const float4* buf = lds[j & 1];
#pragma unroll
    for (int ii = 0; ii < 2; ii++) {
      const int i = j * 2 + ii;
      float4 o4[2];
#pragma unroll
      for (int r = 0; r < 2; r++) o4[r] = he[r][i];
#pragma unroll
      for (int s = 0; s < SDIM; s++) {
        const float4 vv = buf[s * 128 + ii * 64 + lane];
#pragma unroll
        for (int r = 0; r < 2; r++) {
          o4[r].x += acc[r][s] * vv.x;
          o4[r].y += acc[r][s] * vv.y;
          o4[r].z += acc[r][s] * vv.z;
          o4[r].w += acc[r][s] * vv.w;
        }
      }
#pragma unroll
      for (int r = 0; r < 2; r++)
        ((float4*)(out + rowbase + (size_t)r * HDIM))[i * 64 + lane] = o4[r];
    }
  }
}

// ---------------------------------------------------------------------------
extern "C" void kernel_launch(void* const* d_in, const int* in_sizes, int n_in,
                              void* d_out, int out_size, void* d_ws, size_t ws_size,
                              hipStream_t stream) {
  const float* h_e   = (const float*)d_in[0];  // [4,4096,2048]
  const float* h_l   = (const float*)d_in[1];  // [4,10,2048]
  const float* w_q   = (const float*)d_in[2];  // [2048,2048]
  const float* w_k   = (const float*)d_in[3];
  const float* w_v   = (const float*)d_in[4];
  const float* w_o   = (const float*)d_in[5];
  const float* alpha = (const float*)d_in[6];  // scalar
  float* out = (float*)d_out;

  float* ws      = (float*)d_ws;
  float* k_ws    = ws;             // 81920 floats
  float* v_ws    = ws + 81920;
  float* kk_ws   = ws + 163840;
  float* vo_ws   = ws + 245760;
  float* part_ws = ws + 327680;    // 16*4*10*2048 = 1310720 floats (5.2 MB)

  kv_kernel<<<512, 256, 0, stream>>>(h_l, w_k, w_v, k_ws, v_ws);
  kk_part_kernel<<<dim3(2, 32, BDIM), 256, 0, stream>>>(k_ws, w_q, part_ws);
  vo_kernel<<<512, 256, 0, stream>>>(v_ws, w_o, vo_ws);
  kk_reduce_kernel<<<80, 256, 0, stream>>>(part_ws, kk_ws);
  attn_kernel<<<dim3(512, BDIM), 256, 0, stream>>>(h_e, kk_ws, vo_ws, alpha, out);
}

// Round 4
// 431.091 us; speedup vs baseline: 1.2918x; 1.2918x over previous
//
#include <hip/hip_runtime.h>

#define SDIM 10
#define HDIM 2048
#define LDIM 4096
#define BDIM 4

// 1/sqrt(2048)
#define KSCALE 0.02209708691207961f

// ---------------------------------------------------------------------------
// Kernel 1 (v3): k[b,s,o] = sum_h h_l[b,s,h]*w_k[o,h]; v likewise with w_v.
// Block (256 thr, 4 waves) stages h_l[b] (80 KB) in LDS per batch; each wave
// owns an o-pair. Inner loop's ONLY global loads are 4 coalesced weight
// float4 reads -> deep pipelining, no vmcnt contention (h via ds_read_b128).
// Per-lane accumulation order identical to the original v1 -> bitwise-same k,v.
// acc = 40 VGPR; no spill. 256 blocks = 1/CU.
// ---------------------------------------------------------------------------
__global__ __launch_bounds__(256) void kv_kernel(
    const float* __restrict__ h_l, const float* __restrict__ w_k,
    const float* __restrict__ w_v, float* __restrict__ k_out,
    float* __restrict__ v_out) {
  const int wave = threadIdx.x >> 6;
  const int lane = threadIdx.x & 63;
  const int o0 = blockIdx.x * 8 + wave * 2;

  __shared__ float4 hsh[512 * SDIM];  // 80 KB: h_l[b] as [s][512]

  const float4* wk0 = (const float4*)(w_k + (size_t)o0 * HDIM);
  const float4* wk1 = (const float4*)(w_k + (size_t)(o0 + 1) * HDIM);
  const float4* wv0 = (const float4*)(w_v + (size_t)o0 * HDIM);
  const float4* wv1 = (const float4*)(w_v + (size_t)(o0 + 1) * HDIM);

  for (int b = 0; b < BDIM; b++) {
    __syncthreads();  // prior batch's reads of hsh done
    const float4* src = (const float4*)(h_l + (size_t)b * SDIM * HDIM);
    for (int i = threadIdx.x; i < 512 * SDIM; i += 256) hsh[i] = src[i];
    __syncthreads();

    float ak0[SDIM], ak1[SDIM], av0[SDIM], av1[SDIM];
#pragma unroll
    for (int s = 0; s < SDIM; s++) { ak0[s] = ak1[s] = av0[s] = av1[s] = 0.f; }

#pragma unroll
    for (int j = 0; j < 8; j++) {
      const int idx = j * 64 + lane;
      const float4 a0 = wk0[idx], a1 = wk1[idx];
      const float4 c0 = wv0[idx], c1 = wv1[idx];
#pragma unroll
      for (int s = 0; s < SDIM; s++) {
        const float4 h = hsh[s * 512 + idx];
        ak0[s] += a0.x * h.x + a0.y * h.y + a0.z * h.z + a0.w * h.w;
        ak1[s] += a1.x * h.x + a1.y * h.y + a1.z * h.z + a1.w * h.w;
        av0[s] += c0.x * h.x + c0.y * h.y + c0.z * h.z + c0.w * h.w;
        av1[s] += c1.x * h.x + c1.y * h.y + c1.z * h.z + c1.w * h.w;
      }
    }
#pragma unroll
    for (int s = 0; s < SDIM; s++) {
#pragma unroll
      for (int d = 1; d < 64; d <<= 1) {
        ak0[s] += __shfl_xor(ak0[s], d);
        ak1[s] += __shfl_xor(ak1[s], d);
        av0[s] += __shfl_xor(av0[s], d);
        av1[s] += __shfl_xor(av1[s], d);
      }
    }
    if (lane == 0) {
#pragma unroll
      for (int s = 0; s < SDIM; s++) {
        const size_t base = ((size_t)b * SDIM + s) * HDIM + o0;
        k_out[base]     = ak0[s];
        k_out[base + 1] = ak1[s];
        v_out[base]     = av0[s];
        v_out[base + 1] = av1[s];
      }
    }
  }
}

// ---------------------------------------------------------------------------
// Kernel 2a: kk partials. kk[b,s,h] = sum_o k[b,s,o]*w_q[o,h]. (unchanged)
// ---------------------------------------------------------------------------
#define OSPLIT 16
__global__ __launch_bounds__(256) void kk_part_kernel(
    const float* __restrict__ k_in, const float* __restrict__ w_q,
    float* __restrict__ part) {
  const int b = blockIdx.z;
  const int oc = blockIdx.y >> 1;
  const int s0 = (blockIdx.y & 1) * 5;
  const int f4 = blockIdx.x * 256 + threadIdx.x;  // float4 index in [0,512)

  __shared__ float ksh[5 * 128];
  for (int idx = threadIdx.x; idx < 5 * 128; idx += 256) {
    const int s = idx >> 7, oo = idx & 127;
    ksh[idx] = k_in[((size_t)b * SDIM + s0 + s) * HDIM + oc * 128 + oo];
  }
  __syncthreads();

  float4 acc[5];
#pragma unroll
  for (int s = 0; s < 5; s++) acc[s] = make_float4(0.f, 0.f, 0.f, 0.f);

  const float4* wq4 = (const float4*)w_q;
  for (int oo = 0; oo < 128; oo++) {
    const float4 w = wq4[(size_t)(oc * 128 + oo) * 512 + f4];
#pragma unroll
    for (int s = 0; s < 5; s++) {
      const float kv = ksh[s * 128 + oo];
      acc[s].x += kv * w.x; acc[s].y += kv * w.y;
      acc[s].z += kv * w.z; acc[s].w += kv * w.w;
    }
  }
#pragma unroll
  for (int s = 0; s < 5; s++) {
    ((float4*)part)[(((size_t)oc * BDIM + b) * SDIM + s0 + s) * 512 + f4] = acc[s];
  }
}

// Kernel 2b: reduce 16 partials -> kk. (unchanged)
__global__ __launch_bounds__(256) void kk_reduce_kernel(
    const float* __restrict__ part, float* __restrict__ kk_out) {
  const int t = blockIdx.x * 256 + threadIdx.x;  // [0, 20480)
  const float4* p4 = (const float4*)part;
  float4 acc = make_float4(0.f, 0.f, 0.f, 0.f);
#pragma unroll
  for (int p = 0; p < OSPLIT; p++) {
    const float4 v = p4[(size_t)p * 20480 + t];
    acc.x += v.x; acc.y += v.y; acc.z += v.z; acc.w += v.w;
  }
  ((float4*)kk_out)[t] = acc;
}

// ---------------------------------------------------------------------------
// Kernel 3 (v3): vo[b,s,o] = sum_h v[b,s,h]*w_o[o,h]. Same LDS-staged
// structure as kv v3 (v[b] staged per batch; wave owns o-pair; only global
// loads in inner loop are 2 coalesced weight reads). Bitwise-same vo as v1.
// ---------------------------------------------------------------------------
__global__ __launch_bounds__(256) void vo_kernel(
    const float* __restrict__ v_in, const float* __restrict__ w_o,
    float* __restrict__ vo_out) {
  const int wave = threadIdx.x >> 6;
  const int lane = threadIdx.x & 63;
  const int o0 = blockIdx.x * 8 + wave * 2;

  __shared__ float4 vsh[512 * SDIM];  // 80 KB

  const float4* wo0 = (const float4*)(w_o + (size_t)o0 * HDIM);
  const float4* wo1 = (const float4*)(w_o + (size_t)(o0 + 1) * HDIM);

  for (int b = 0; b < BDIM; b++) {
    __syncthreads();
    const float4* src = (const float4*)(v_in + (size_t)b * SDIM * HDIM);
    for (int i = threadIdx.x; i < 512 * SDIM; i += 256) vsh[i] = src[i];
    __syncthreads();

    float a0[SDIM], a1[SDIM];
#pragma unroll
    for (int s = 0; s < SDIM; s++) { a0[s] = a1[s] = 0.f; }

#pragma unroll
    for (int j = 0; j < 8; j++) {
      const int idx = j * 64 + lane;
      const float4 w0 = wo0[idx], w1 = wo1[idx];
#pragma unroll
      for (int s = 0; s < SDIM; s++) {
        const float4 h = vsh[s * 512 + idx];
        a0[s] += w0.x * h.x + w0.y * h.y + w0.z * h.z + w0.w * h.w;
        a1[s] += w1.x * h.x + w1.y * h.y + w1.z * h.z + w1.w * h.w;
      }
    }
#pragma unroll
    for (int s = 0; s < SDIM; s++) {
#pragma unroll
      for (int d = 1; d < 64; d <<= 1) {
        a0[s] += __shfl_xor(a0[s], d);
        a1[s] += __shfl_xor(a1[s], d);
      }
    }
    if (lane == 0) {
#pragma unroll
      for (int s = 0; s < SDIM; s++) {
        const size_t base = ((size_t)b * SDIM + s) * HDIM + o0;
        vo_out[base]     = a0[s];
        vo_out[base + 1] = a1[s];
      }
    }
  }
}

// ---------------------------------------------------------------------------
// Kernel 4 (main) v4: unchanged from round 3 (global_load_lds double-buffered
// staging; no VGPR round-trip). Expect it as top dispatch this round; verify
// WRITE_SIZE == 131072 KB exactly (no spill).
// ---------------------------------------------------------------------------
__device__ __forceinline__ void stage_chunk(const float4* __restrict__ src,
                                            float4* lds_base, int j, int tid,
                                            int wave) {
#pragma unroll
  for (int k = 0; k < 5; k++) {
    const int idx = k * 256 + tid;
    const float4* g = src + (size_t)(idx >> 7) * 512 + j * 128 + (idx & 127);
    float4* l = lds_base + k * 256 + (wave << 6);
    __builtin_amdgcn_global_load_lds(
        (const __attribute__((address_space(1))) void*)g,
        (__attribute__((address_space(3))) void*)l, 16, 0, 0);
  }
}

__global__ __launch_bounds__(256, 3) void attn_kernel(
    const float* __restrict__ h_e, const float* __restrict__ kk,
    const float* __restrict__ vo, const float* __restrict__ alpha_p,
    float* __restrict__ out) {
  const int b = blockIdx.y;
  const int wave = threadIdx.x >> 6;
  const int lane = threadIdx.x & 63;
  const int tid = threadIdx.x;
  const int row0 = blockIdx.x * 8 + wave * 2;
  const float alpha = *alpha_p;
  const float4* kkb = (const float4*)(kk + (size_t)b * SDIM * HDIM);
  const float4* vob = (const float4*)(vo + (size_t)b * SDIM * HDIM);
  const size_t rowbase = ((size_t)b * LDIM + row0) * HDIM;

  __shared__ float4 lds[2][SDIM * 128];  // 2 x 20 KB

  float4 he[2][8];
#pragma unroll
  for (int r = 0; r < 2; r++) {
    const float4* src = (const float4*)(h_e + rowbase + (size_t)r * HDIM);
#pragma unroll
    for (int i = 0; i < 8; i++) he[r][i] = src[i * 64 + lane];
  }

  float acc[2][SDIM];
#pragma unroll
  for (int r = 0; r < 2; r++)
#pragma unroll
    for (int s = 0; s < SDIM; s++) acc[r][s] = 0.f;

  // ---- QK phase ----
  stage_chunk(kkb, lds[0], 0, tid, wave);
#pragma unroll
  for (int j = 0; j < 4; j++) {
    __syncthreads();  // drains vmem: chunk j landed; buf (j+1)&1 consumed
    if (j < 3) stage_chunk(kkb, lds[(j + 1) & 1], j + 1, tid, wave);
    const float4* buf = lds[j & 1];
#pragma unroll
    for (int ii = 0; ii < 2; ii++) {
      const int i = j * 2 + ii;
#pragma unroll
      for (int s = 0; s < SDIM; s++) {
        const float4 kv = buf[s * 128 + ii * 64 + lane];
#pragma unroll
        for (int r = 0; r < 2; r++)
          acc[r][s] += he[r][i].x * kv.x + he[r][i].y * kv.y +
                       he[r][i].z * kv.z + he[r][i].w * kv.w;
      }
    }
  }

  // ---- scores -> softmax (per-wave) ----
#pragma unroll
  for (int r = 0; r < 2; r++)
#pragma unroll
    for (int s = 0; s < SDIM; s++) {
      float v = acc[r][s];
      v += __shfl_xor(v, 1);
      v += __shfl_xor(v, 2);
      v += __shfl_xor(v, 4);
      v += __shfl_xor(v, 8);
      v += __shfl_xor(v, 16);
      v += __shfl_xor(v, 32);
      acc[r][s] = v * KSCALE;
    }
#pragma unroll
  for (int r = 0; r < 2; r++) {
    float m = acc[r][0];
#pragma unroll
    for (int s = 1; s < SDIM; s++) m = fmaxf(m, acc[r][s]);
    float sum = 0.f;
#pragma unroll
    for (int s = 0; s < SDIM; s++) {
      acc[r][s] = __expf(acc[r][s] - m);
      sum += acc[r][s];
    }
    const float inv = alpha / sum;
#pragma unroll
    for (int s = 0; s < SDIM; s++) acc[r][s] *= inv;
  }

  // ---- PV phase ----
  stage_chunk(vob, lds[0], 0, tid, wave);
#pragma unroll
  for (int j = 0; j < 4; j++) {
    __syncthreads();
    if (j < 3) stage_chunk(vob, lds[(j + 1) & 1], j + 1, tid, wave);
    const float4* buf = lds[j & 1];
#pragma unroll
    for (int ii = 0; ii < 2; ii++) {
      const int i = j * 2 + ii;
      float4 o4[2];
#pragma unroll
      for (int r = 0; r < 2; r++) o4[r] = he[r][i];
#pragma unroll
      for (int s = 0; s < SDIM; s++) {
        const float4 vv = buf[s * 128 + ii * 64 + lane];
#pragma unroll
        for (int r = 0; r < 2; r++) {
          o4[r].x += acc[r][s] * vv.x;
          o4[r].y += acc[r][s] * vv.y;
          o4[r].z += acc[r][s] * vv.z;
          o4[r].w += acc[r][s] * vv.w;
        }
      }
#pragma unroll
      for (int r = 0; r < 2; r++)
        ((float4*)(out + rowbase + (size_t)r * HDIM))[i * 64 + lane] = o4[r];
    }
  }
}

// ---------------------------------------------------------------------------
extern "C" void kernel_launch(void* const* d_in, const int* in_sizes, int n_in,
                              void* d_out, int out_size, void* d_ws, size_t ws_size,
                              hipStream_t stream) {
  const float* h_e   = (const float*)d_in[0];  // [4,4096,2048]
  const float* h_l   = (const float*)d_in[1];  // [4,10,2048]
  const float* w_q   = (const float*)d_in[2];  // [2048,2048]
  const float* w_k   = (const float*)d_in[3];
  const float* w_v   = (const float*)d_in[4];
  const float* w_o   = (const float*)d_in[5];
  const float* alpha = (const float*)d_in[6];  // scalar
  float* out = (float*)d_out;

  float* ws      = (float*)d_ws;
  float* k_ws    = ws;             // 81920 floats
  float* v_ws    = ws + 81920;
  float* kk_ws   = ws + 163840;
  float* vo_ws   = ws + 245760;
  float* part_ws = ws + 327680;    // 16*4*10*2048 = 1310720 floats (5.2 MB)

  kv_kernel<<<256, 256, 0, stream>>>(h_l, w_k, w_v, k_ws, v_ws);
  kk_part_kernel<<<dim3(2, 32, BDIM), 256, 0, stream>>>(k_ws, w_q, part_ws);
  vo_kernel<<<256, 256, 0, stream>>>(v_ws, w_o, vo_ws);
  kk_reduce_kernel<<<80, 256, 0, stream>>>(part_ws, kk_ws);
  attn_kernel<<<dim3(512, BDIM), 256, 0, stream>>>(h_e, kk_ws, vo_ws, alpha, out);
}